// Round 8
// baseline (206.668 us; speedup 1.0000x reference)
//
#include <hip/hip_runtime.h>

// SpatialNonIntersectionAxiom: B=8, N=512, E=4096.
// Outputs (flat f32): [0] = loss, [1 .. 1+E*E) = violation_mask (0/1),
// [1+E*E .. 1+2*E*E) = violation_scores.
//
// Structure:
//   1. edge_pre: per-edge records + batch histogram (batch = src >> 9).
//   2. zero_fill: streaming float4 zero of both output planes (+8-entry
//      exclusive prefix of the histogram, done by one thread).
//   3. edge_scatter: bucket edges by batch (wave-aggregated atomics).
//   4. pair_kernel: evaluate ONLY unordered intra-batch pairs (~1M of
//      16.7M), oriented to (min,max) original index; mask path and seg
//      path bitwise-identical to the reference; sparse scatter of the
//      rare nonzero results; bucketed loss reduction.
//   5. finalize: loss = sum / max(n_pairs, 1).

#define EDGES   4096
#define LOGE    12
#define EPS     0.001f
#define PROX    0.15f
#define NBUCKET 2048
#define ACHUNK  16
#define MAXC    1024   // safety cap on edges per batch (expected ~512)

// ---------------- per-edge records + batch histogram ----------------
// rec1 = {a1x, a1y, d1x, d1y}
// rec2 = {midx, midy, half, dda(=d1.a1)}
// rec3 = {sq, bitcast(src), bitcast(dst), 0}
__global__ __launch_bounds__(256) void edge_pre(
    const float2* __restrict__ pos,
    const int*    __restrict__ esrc,
    const int*    __restrict__ edst,
    float4* __restrict__ rec1, float4* __restrict__ rec2, float4* __restrict__ rec3,
    unsigned* __restrict__ bcount)
{
#pragma clang fp contract(off)
    const int e = blockIdx.x * 256 + threadIdx.x;
    const int s = esrc[e], d = edst[e];
    const float2 a1 = pos[s], a2 = pos[d];
    const float d1x = a2.x - a1.x, d1y = a2.y - a1.y;
    const float midx = (a1.x + a2.x) * 0.5f, midy = (a1.y + a2.y) * 0.5f;
    const float half = sqrtf(d1x * d1x + d1y * d1y) * 0.5f;
    const float sq   = fmaxf(d1x * d1x + d1y * d1y, 1e-12f);
    const float dda  = d1x * a1.x + d1y * a1.y;
    rec1[e] = make_float4(a1.x, a1.y, d1x, d1y);
    rec2[e] = make_float4(midx, midy, half, dda);
    rec3[e] = make_float4(sq, __int_as_float(s), __int_as_float(d), 0.0f);

    const int bv   = s >> 9;
    const int lane = threadIdx.x & 63;
    #pragma unroll
    for (int v = 0; v < 8; ++v) {
        const unsigned long long mk = __ballot(bv == v);
        if (mk && lane == (__ffsll((long long)mk) - 1))
            atomicAdd(&bcount[v], (unsigned)__popcll(mk));
    }
}

// ---------------- streaming zero-fill + histogram prefix ----------------
#define ZF_BLOCKS 2048
#define ZF_T      (ZF_BLOCKS * 256)
#define ZF_QUADS  8388607u                   // float4s covering out[4 .. 33554432)
__global__ __launch_bounds__(256) void zero_fill(
    float* __restrict__ out,
    const unsigned* __restrict__ bcount, unsigned* __restrict__ boffset)
{
    const unsigned g = blockIdx.x * 256 + threadIdx.x;
    if (g == 0) {                            // 8-entry exclusive prefix
        unsigned acc = 0;
        #pragma unroll
        for (int v = 0; v < 8; ++v) { boffset[v] = acc; acc += bcount[v]; }
        out[1] = 0.0f; out[2] = 0.0f; out[3] = 0.0f;
        out[2 * EDGES * EDGES] = 0.0f;
    }
    float4* __restrict__ base = (float4*)(out + 4);
    const float4 z4 = make_float4(0.0f, 0.0f, 0.0f, 0.0f);
    #pragma unroll
    for (unsigned p = 0; p < 16; ++p) {
        const unsigned idx = g + p * (unsigned)ZF_T;
        if (idx < ZF_QUADS) base[idx] = z4;
    }
}

// ---------------- scatter edges into batch-sorted slots ----------------
__global__ __launch_bounds__(256) void edge_scatter(
    const float4* __restrict__ rec1, const float4* __restrict__ rec2,
    const float4* __restrict__ rec3,
    const unsigned* __restrict__ boffset, unsigned* __restrict__ bcursor,
    float4* __restrict__ srec1, float4* __restrict__ srec2,
    float4* __restrict__ srec3, unsigned* __restrict__ sorig)
{
    const int e    = blockIdx.x * 256 + threadIdx.x;
    const int lane = threadIdx.x & 63;
    const unsigned long long ltmask = (1ull << lane) - 1ull;
    const float4 r3 = rec3[e];
    const int bv = __float_as_int(r3.y) >> 9;

    unsigned slot = 0;
    #pragma unroll
    for (int v = 0; v < 8; ++v) {
        const unsigned long long mk = __ballot(bv == v);
        if (mk) {
            const int leader = __ffsll((long long)mk) - 1;
            unsigned basev = 0;
            if (lane == leader) basev = atomicAdd(&bcursor[v], (unsigned)__popcll(mk));
            basev = (unsigned)__shfl((int)basev, leader, 64);
            if (bv == v) slot = boffset[v] + basev + (unsigned)__popcll(mk & ltmask);
        }
    }
    srec1[slot] = rec1[e];
    srec2[slot] = rec2[e];
    srec3[slot] = r3;
    sorig[slot] = (unsigned)e;
}

// ---------------- pair kernel: intra-batch unordered pairs only ----------------
// grid = (MAXC/ACHUNK, MAXC/256, 8). Thread owns one b-slot; loops ACHUNK
// uniform a-slots. Evaluates pair once with (i,j) = (min,max) orig index.
__global__ __launch_bounds__(256) void pair_kernel(
    const float4* __restrict__ srec1, const float4* __restrict__ srec2,
    const float4* __restrict__ srec3, const unsigned* __restrict__ sorig,
    const unsigned* __restrict__ bcount, const unsigned* __restrict__ boffset,
    float* __restrict__ out,
    float* __restrict__ bsum, unsigned* __restrict__ bcnt)
{
#pragma clang fp contract(off)
    const int bz   = blockIdx.z;                 // batch
    const int cnt  = (int)bcount[bz];
    const int off  = (int)boffset[bz];
    const int abase = blockIdx.x * ACHUNK;
    const int bbase = blockIdx.y * 256;
    if (abase >= cnt || bbase >= cnt) return;
    if (abase >= bbase + 256) return;            // no a < b possible

    float* __restrict__ o_mask  = out + 1;
    float* __restrict__ o_score = out + 1 + EDGES * EDGES;

    const int tid  = threadIdx.x;
    const int bidx = bbase + tid;                // sorted slot (within batch)
    const bool havb = bidx < cnt;

    float4 br1, br2, br3; int ob = 0;
    if (havb) {
        br1 = srec1[off + bidx]; br2 = srec2[off + bidx]; br3 = srec3[off + bidx];
        ob  = (int)sorig[off + bidx];
    }
    const int bs = havb ? __float_as_int(br3.y) : -1;
    const int bd = havb ? __float_as_int(br3.z) : -1;

    float vsum = 0.0f;
    int   vcnt = 0;

    const int aend = (abase + ACHUNK < cnt) ? abase + ACHUNK : cnt;
    for (int aa = abase; aa < aend; ++aa) {
        const int slotA = off + aa;                          // block-uniform
        const float4 ar1 = srec1[slotA], ar2 = srec2[slotA], ar3 = srec3[slotA];
        const int oa = (int)sorig[slotA];
        const int as_ = __float_as_int(ar3.y), ad = __float_as_int(ar3.z);

        const bool act = havb && (aa < bidx);
        if (!__ballot(act)) continue;
        if (act) {
            // ---- mask (orientation-invariant bitwise; sameb & upper by construction)
            const float dmx = ar2.x - br2.x, dmy = ar2.y - br2.y;
            const float dist  = sqrtf(dmx * dmx + dmy * dmy);
            const float reach = ar2.z + br2.z + PROX;
            const bool shares = (as_ == bs) | (as_ == bd) | (ad == bs) | (ad == bd);
            const bool m = (dist < reach) & (!shares);
            vcnt += m ? 1 : 0;
            if (m) {
                // ---- orient to reference roles: i = min orig, j = max orig
                const bool ai = oa < ob;
                const float4 r1i = ai ? ar1 : br1, r2i = ai ? ar2 : br2, r3i = ai ? ar3 : br3;
                const float4 r1j = ai ? br1 : ar1, r2j = ai ? br2 : ar2, r3j = ai ? br3 : ar3;

                // ---- segment distance: reference op order, IEEE div/sqrt, no FMA
                const float sqi = r3i.x, sqj = r3j.x;
                const float b = r1i.z * r1j.z + r1i.w * r1j.w;
                const float c = r2i.w - (r1i.z * r1j.x + r1i.w * r1j.y);
                const float f = (r1i.x * r1j.z + r1i.y * r1j.w) - r2j.w;
                const float denom = fmaxf(sqi * sqj - b * b, 1e-12f);

                float s = (b * f - c * sqj) / denom;
                s = fminf(fmaxf(s, 0.0f), 1.0f);
                const float t = fminf(fmaxf((b * s + f) / sqj, 0.0f), 1.0f);
                s = fminf(fmaxf((b * t - c) / sqi, 0.0f), 1.0f);

                const float cax = r1i.x + s * r1i.z, cay = r1i.y + s * r1i.w;
                const float cbx = r1j.x + t * r1j.z, cby = r1j.y + t * r1j.w;
                const float dx = cax - cbx, dy = cay - cby;
                const float dmin = sqrtf(dx * dx + dy * dy);

                const float pl = fmaxf(EPS - dmin, 0.0f);
                if (pl > 0.0f) {
                    const int io = ai ? oa : ob, jo = ai ? ob : oa;
                    const int k  = (io << LOGE) | jo;
                    o_mask[k]  = 1.0f;
                    o_score[k] = pl;
                    vsum += pl;
                }
            }
        }
    }

    // ---- block reduction: sum(pair_loss), count(mask) ----
    #pragma unroll
    for (int o = 32; o > 0; o >>= 1) {
        vsum += __shfl_xor(vsum, o, 64);
        vcnt += __shfl_xor(vcnt, o, 64);
    }
    __shared__ float    ls[4];
    __shared__ unsigned lc[4];
    const int wid = tid >> 6, lane = tid & 63;
    if (lane == 0) { ls[wid] = vsum; lc[wid] = (unsigned)vcnt; }
    __syncthreads();
    if (tid == 0) {
        const float    s4 = ls[0] + ls[1] + ls[2] + ls[3];
        const unsigned c4 = lc[0] + lc[1] + lc[2] + lc[3];
        if (s4 != 0.0f || c4 != 0u) {
            const int bk = (((blockIdx.z * gridDim.y + blockIdx.y) * gridDim.x) + blockIdx.x) & (NBUCKET - 1);
            atomicAdd(&bsum[bk], s4);
            atomicAdd(&bcnt[bk], c4);
        }
    }
}

__global__ __launch_bounds__(256) void finalize_kernel(
    const float* __restrict__ bsum, const unsigned* __restrict__ bcnt,
    float* __restrict__ out)
{
    float    s = 0.0f;
    unsigned c = 0u;
    for (int b = threadIdx.x; b < NBUCKET; b += 256) { s += bsum[b]; c += bcnt[b]; }
    #pragma unroll
    for (int o = 32; o > 0; o >>= 1) {
        s += __shfl_xor(s, o, 64);
        c += (unsigned)__shfl_xor((int)c, o, 64);
    }
    __shared__ float    ls[4];
    __shared__ unsigned lc[4];
    const int wid = threadIdx.x >> 6, lane = threadIdx.x & 63;
    if (lane == 0) { ls[wid] = s; lc[wid] = c; }
    __syncthreads();
    if (threadIdx.x == 0) {
        const float    st = ls[0] + ls[1] + ls[2] + ls[3];
        const unsigned ct = lc[0] + lc[1] + lc[2] + lc[3];
        const unsigned n  = ct > 1u ? ct : 1u;
        out[0] = st / (float)n;
    }
}

extern "C" void kernel_launch(void* const* d_in, const int* in_sizes, int n_in,
                              void* d_out, int out_size, void* d_ws, size_t ws_size,
                              hipStream_t stream) {
    const float2* pos  = (const float2*)d_in[0];   // node_positions (8,512,2)
    // d_in[1] = adjacency: unused
    const int*    esrc = (const int*)d_in[2];       // edge_index[0]
    const int*    edst = esrc + EDGES;              // edge_index[1]

    float*    out     = (float*)d_out;
    char*     ws      = (char*)d_ws;
    float*    bsum    = (float*)ws;                        // 2048 f  @ 0
    unsigned* bcnt    = (unsigned*)(ws + 8192);            // 2048 u  @ 8K
    unsigned* bcount  = (unsigned*)(ws + 16384);           // 8 u
    unsigned* boffset = (unsigned*)(ws + 16384 + 32);      // 8 u
    unsigned* bcursor = (unsigned*)(ws + 16384 + 64);      // 8 u
    float4*   rec1    = (float4*)(ws + 32768);             // 4096 x 16B each
    float4*   rec2    = rec1 + EDGES;
    float4*   rec3    = rec2 + EDGES;
    float4*   srec1   = rec3 + EDGES;
    float4*   srec2   = srec1 + EDGES;
    float4*   srec3   = srec2 + EDGES;
    unsigned* sorig   = (unsigned*)(srec3 + EDGES);

    hipMemsetAsync(d_ws, 0, 16384 + 96, stream);           // bsum,bcnt,counters

    edge_pre<<<EDGES / 256, 256, 0, stream>>>(pos, esrc, edst, rec1, rec2, rec3, bcount);
    zero_fill<<<ZF_BLOCKS, 256, 0, stream>>>(out, bcount, boffset);
    edge_scatter<<<EDGES / 256, 256, 0, stream>>>(rec1, rec2, rec3, boffset, bcursor,
                                                  srec1, srec2, srec3, sorig);
    dim3 grid(MAXC / ACHUNK, MAXC / 256, 8);               // (64, 4, 8)
    pair_kernel<<<grid, 256, 0, stream>>>(srec1, srec2, srec3, sorig,
                                          bcount, boffset, out, bsum, bcnt);
    finalize_kernel<<<1, 256, 0, stream>>>(bsum, bcnt, out);
}

// Round 9
// 183.058 us; speedup vs baseline: 1.1290x; 1.1290x over previous
//
#include <hip/hip_runtime.h>

// SpatialNonIntersectionAxiom: B=8, N=512, E=4096.
// Outputs (flat f32): [0] = loss, [1 .. 1+E*E) = violation_mask (0/1),
// [1+E*E .. 1+2*E*E) = violation_scores.
//
// Structure:
//   1. edge_pre: per-edge records + batch histogram (batch = src >> 9).
//   2. zero_fill: streaming float4 zero of both output planes (+8-entry
//      exclusive prefix of the histogram by thread g==0).
//   3. edge_scatter: bucket edges by batch (wave-aggregated atomics).
//   4. pair_kernel: grid (1024, 8) — one block per (b-slot, batch); threads
//      sweep a < b coalesced. Only intra-batch unordered pairs (~1.05M of
//      16.7M) are evaluated; mask + seg math bitwise-identical to the
//      reference (oriented to (min,max) original index); rare nonzero
//      results scatter-written over the zero background.
//   5. finalize: loss = sum / max(n_pairs, 1).

#define EDGES   4096
#define LOGE    12
#define EPS     0.001f
#define PROX    0.15f
#define NBUCKET 2048
#define MAXC    1024   // grid cap on per-batch edge count (expected ~512)

// ---------------- per-edge records + batch histogram ----------------
// rec1 = {a1x, a1y, d1x, d1y}
// rec2 = {midx, midy, half, dda(=d1.a1)}
// rec3 = {sq, bitcast(src), bitcast(dst), 0}
__global__ __launch_bounds__(256) void edge_pre(
    const float2* __restrict__ pos,
    const int*    __restrict__ esrc,
    const int*    __restrict__ edst,
    float4* __restrict__ rec1, float4* __restrict__ rec2, float4* __restrict__ rec3,
    unsigned* __restrict__ bcount)
{
#pragma clang fp contract(off)
    const int e = blockIdx.x * 256 + threadIdx.x;
    const int s = esrc[e], d = edst[e];
    const float2 a1 = pos[s], a2 = pos[d];
    const float d1x = a2.x - a1.x, d1y = a2.y - a1.y;
    const float midx = (a1.x + a2.x) * 0.5f, midy = (a1.y + a2.y) * 0.5f;
    const float half = sqrtf(d1x * d1x + d1y * d1y) * 0.5f;
    const float sq   = fmaxf(d1x * d1x + d1y * d1y, 1e-12f);
    const float dda  = d1x * a1.x + d1y * a1.y;
    rec1[e] = make_float4(a1.x, a1.y, d1x, d1y);
    rec2[e] = make_float4(midx, midy, half, dda);
    rec3[e] = make_float4(sq, __int_as_float(s), __int_as_float(d), 0.0f);

    const int bv   = s >> 9;
    const int lane = threadIdx.x & 63;
    #pragma unroll
    for (int v = 0; v < 8; ++v) {
        const unsigned long long mk = __ballot(bv == v);
        if (mk && lane == (__ffsll((long long)mk) - 1))
            atomicAdd(&bcount[v], (unsigned)__popcll(mk));
    }
}

// ---------------- streaming zero-fill + histogram prefix ----------------
#define ZF_BLOCKS 2048
#define ZF_T      (ZF_BLOCKS * 256)
#define ZF_QUADS  8388607u                   // float4s covering out[4 .. 33554432)
__global__ __launch_bounds__(256) void zero_fill(
    float* __restrict__ out,
    const unsigned* __restrict__ bcount, unsigned* __restrict__ boffset)
{
    const unsigned g = blockIdx.x * 256 + threadIdx.x;
    if (g == 0) {                            // 8-entry exclusive prefix
        unsigned acc = 0;
        #pragma unroll
        for (int v = 0; v < 8; ++v) { boffset[v] = acc; acc += bcount[v]; }
        out[1] = 0.0f; out[2] = 0.0f; out[3] = 0.0f;
        out[2 * EDGES * EDGES] = 0.0f;
    }
    float4* __restrict__ base = (float4*)(out + 4);
    const float4 z4 = make_float4(0.0f, 0.0f, 0.0f, 0.0f);
    #pragma unroll
    for (unsigned p = 0; p < 16; ++p) {
        const unsigned idx = g + p * (unsigned)ZF_T;
        if (idx < ZF_QUADS) base[idx] = z4;
    }
}

// ---------------- scatter edges into batch-sorted slots ----------------
__global__ __launch_bounds__(256) void edge_scatter(
    const float4* __restrict__ rec1, const float4* __restrict__ rec2,
    const float4* __restrict__ rec3,
    const unsigned* __restrict__ boffset, unsigned* __restrict__ bcursor,
    float4* __restrict__ srec1, float4* __restrict__ srec2,
    float4* __restrict__ srec3, unsigned* __restrict__ sorig)
{
    const int e    = blockIdx.x * 256 + threadIdx.x;
    const int lane = threadIdx.x & 63;
    const unsigned long long ltmask = (1ull << lane) - 1ull;
    const float4 r3 = rec3[e];
    const int bv = __float_as_int(r3.y) >> 9;

    unsigned slot = 0;
    #pragma unroll
    for (int v = 0; v < 8; ++v) {
        const unsigned long long mk = __ballot(bv == v);
        if (mk) {
            const int leader = __ffsll((long long)mk) - 1;
            unsigned basev = 0;
            if (lane == leader) basev = atomicAdd(&bcursor[v], (unsigned)__popcll(mk));
            basev = (unsigned)__shfl((int)basev, leader, 64);
            if (bv == v) slot = boffset[v] + basev + (unsigned)__popcll(mk & ltmask);
        }
    }
    srec1[slot] = rec1[e];
    srec2[slot] = rec2[e];
    srec3[slot] = r3;
    sorig[slot] = (unsigned)e;
}

// ------- pair kernel: one block per (b-slot, batch); threads sweep a < b -------
__global__ __launch_bounds__(256) void pair_kernel(
    const float4* __restrict__ srec1, const float4* __restrict__ srec2,
    const float4* __restrict__ srec3, const unsigned* __restrict__ sorig,
    const unsigned* __restrict__ bcount, const unsigned* __restrict__ boffset,
    float* __restrict__ out,
    float* __restrict__ bsum, unsigned* __restrict__ bcnt)
{
#pragma clang fp contract(off)
    const int bz  = blockIdx.y;                  // batch
    const int b   = blockIdx.x;                  // b-slot within batch
    const int cnt = (int)bcount[bz];
    if (b == 0 || b >= cnt) return;
    const int off = (int)boffset[bz];

    float* __restrict__ o_mask  = out + 1;
    float* __restrict__ o_score = out + 1 + EDGES * EDGES;

    // block-uniform b-record
    const float4 br1 = srec1[off + b], br2 = srec2[off + b], br3 = srec3[off + b];
    const int ob = (int)sorig[off + b];
    const int bs = __float_as_int(br3.y), bd = __float_as_int(br3.z);

    float vsum = 0.0f;
    int   vcnt = 0;

    for (int a = threadIdx.x; a < b; a += 256) {
        const int slotA = off + a;               // coalesced across the wave
        const float4 ar2 = srec2[slotA];
        const float4 ar3 = srec3[slotA];
        const int as_ = __float_as_int(ar3.y), ad = __float_as_int(ar3.z);

        // ---- mask (orientation-invariant bitwise; sameb/upper by construction)
        const float dmx = ar2.x - br2.x, dmy = ar2.y - br2.y;
        const float dist  = sqrtf(dmx * dmx + dmy * dmy);
        const float reach = ar2.z + br2.z + PROX;
        const bool shares = (as_ == bs) | (as_ == bd) | (ad == bs) | (ad == bd);
        const bool m = (dist < reach) & (!shares);
        vcnt += m ? 1 : 0;
        if (m) {
            const float4 ar1 = srec1[slotA];
            const int oa = (int)sorig[slotA];
            // ---- orient to reference roles: i = min orig index, j = max
            const bool ai = oa < ob;
            const float4 r1i = ai ? ar1 : br1, r2i = ai ? ar2 : br2, r3i = ai ? ar3 : br3;
            const float4 r1j = ai ? br1 : ar1, r2j = ai ? br2 : ar2, r3j = ai ? br3 : ar3;

            // ---- segment distance: reference op order, IEEE div/sqrt, no FMA
            const float sqi = r3i.x, sqj = r3j.x;
            const float bb = r1i.z * r1j.z + r1i.w * r1j.w;
            const float c  = r2i.w - (r1i.z * r1j.x + r1i.w * r1j.y);
            const float f  = (r1i.x * r1j.z + r1i.y * r1j.w) - r2j.w;
            const float denom = fmaxf(sqi * sqj - bb * bb, 1e-12f);

            float s = (bb * f - c * sqj) / denom;
            s = fminf(fmaxf(s, 0.0f), 1.0f);
            const float t = fminf(fmaxf((bb * s + f) / sqj, 0.0f), 1.0f);
            s = fminf(fmaxf((bb * t - c) / sqi, 0.0f), 1.0f);

            const float cax = r1i.x + s * r1i.z, cay = r1i.y + s * r1i.w;
            const float cbx = r1j.x + t * r1j.z, cby = r1j.y + t * r1j.w;
            const float dx = cax - cbx, dy = cay - cby;
            const float dmin = sqrtf(dx * dx + dy * dy);

            const float pl = fmaxf(EPS - dmin, 0.0f);
            if (pl > 0.0f) {
                const int io = ai ? oa : ob, jo = ai ? ob : oa;
                const int k  = (io << LOGE) | jo;
                o_mask[k]  = 1.0f;
                o_score[k] = pl;
                vsum += pl;
            }
        }
    }

    // ---- block reduction: sum(pair_loss), count(mask) ----
    #pragma unroll
    for (int o = 32; o > 0; o >>= 1) {
        vsum += __shfl_xor(vsum, o, 64);
        vcnt += __shfl_xor(vcnt, o, 64);
    }
    __shared__ float    ls[4];
    __shared__ unsigned lc[4];
    const int wid = threadIdx.x >> 6, lane = threadIdx.x & 63;
    if (lane == 0) { ls[wid] = vsum; lc[wid] = (unsigned)vcnt; }
    __syncthreads();
    if (threadIdx.x == 0) {
        const float    s4 = ls[0] + ls[1] + ls[2] + ls[3];
        const unsigned c4 = lc[0] + lc[1] + lc[2] + lc[3];
        if (s4 != 0.0f || c4 != 0u) {
            const int bk = (blockIdx.y * MAXC + blockIdx.x) & (NBUCKET - 1);
            atomicAdd(&bsum[bk], s4);
            atomicAdd(&bcnt[bk], c4);
        }
    }
}

__global__ __launch_bounds__(256) void finalize_kernel(
    const float* __restrict__ bsum, const unsigned* __restrict__ bcnt,
    float* __restrict__ out)
{
    float    s = 0.0f;
    unsigned c = 0u;
    for (int b = threadIdx.x; b < NBUCKET; b += 256) { s += bsum[b]; c += bcnt[b]; }
    #pragma unroll
    for (int o = 32; o > 0; o >>= 1) {
        s += __shfl_xor(s, o, 64);
        c += (unsigned)__shfl_xor((int)c, o, 64);
    }
    __shared__ float    ls[4];
    __shared__ unsigned lc[4];
    const int wid = threadIdx.x >> 6, lane = threadIdx.x & 63;
    if (lane == 0) { ls[wid] = s; lc[wid] = c; }
    __syncthreads();
    if (threadIdx.x == 0) {
        const float    st = ls[0] + ls[1] + ls[2] + ls[3];
        const unsigned ct = lc[0] + lc[1] + lc[2] + lc[3];
        const unsigned n  = ct > 1u ? ct : 1u;
        out[0] = st / (float)n;
    }
}

extern "C" void kernel_launch(void* const* d_in, const int* in_sizes, int n_in,
                              void* d_out, int out_size, void* d_ws, size_t ws_size,
                              hipStream_t stream) {
    const float2* pos  = (const float2*)d_in[0];   // node_positions (8,512,2)
    // d_in[1] = adjacency: unused
    const int*    esrc = (const int*)d_in[2];       // edge_index[0]
    const int*    edst = esrc + EDGES;              // edge_index[1]

    float*    out     = (float*)d_out;
    char*     ws      = (char*)d_ws;
    float*    bsum    = (float*)ws;                        // 2048 f  @ 0
    unsigned* bcnt    = (unsigned*)(ws + 8192);            // 2048 u  @ 8K
    unsigned* bcount  = (unsigned*)(ws + 16384);           // 8 u
    unsigned* boffset = (unsigned*)(ws + 16384 + 32);      // 8 u
    unsigned* bcursor = (unsigned*)(ws + 16384 + 64);      // 8 u
    float4*   rec1    = (float4*)(ws + 32768);             // 4096 x 16B each
    float4*   rec2    = rec1 + EDGES;
    float4*   rec3    = rec2 + EDGES;
    float4*   srec1   = rec3 + EDGES;
    float4*   srec2   = srec1 + EDGES;
    float4*   srec3   = srec2 + EDGES;
    unsigned* sorig   = (unsigned*)(srec3 + EDGES);

    hipMemsetAsync(d_ws, 0, 16384 + 96, stream);           // bsum,bcnt,counters

    edge_pre<<<EDGES / 256, 256, 0, stream>>>(pos, esrc, edst, rec1, rec2, rec3, bcount);
    zero_fill<<<ZF_BLOCKS, 256, 0, stream>>>(out, bcount, boffset);
    edge_scatter<<<EDGES / 256, 256, 0, stream>>>(rec1, rec2, rec3, boffset, bcursor,
                                                  srec1, srec2, srec3, sorig);
    dim3 grid(MAXC, 8);                                    // one block per (b-slot, batch)
    pair_kernel<<<grid, 256, 0, stream>>>(srec1, srec2, srec3, sorig,
                                          bcount, boffset, out, bsum, bcnt);
    finalize_kernel<<<1, 256, 0, stream>>>(bsum, bcnt, out);
}